// Round 16
// baseline (112.676 us; speedup 1.0000x reference)
//
#include <hip/hip_runtime.h>
#include <hip/hip_bf16.h>

#define BATCH 4
#define NPTS  4096
#define KNBR  20
#define INC   32
#define TWC   64   // 2*INC
#define OUTC  32
#define EPSBN 1e-5f

typedef short short8 __attribute__((ext_vector_type(8)));
typedef float f32x16 __attribute__((ext_vector_type(16)));

// ---------------- helpers ----------------
__device__ __forceinline__ float rlf(float v, int l) {
    return __uint_as_float((unsigned)__builtin_amdgcn_readlane((int)__float_as_uint(v), l));
}
__device__ __forceinline__ ushort f2bf(float x) {        // fp32 -> bf16 bits (RNE)
    unsigned u = __float_as_uint(x);
    unsigned r = u + 0x7FFFu + ((u >> 16) & 1u);
    return (ushort)(r >> 16);
}
__device__ __forceinline__ float bf2f(ushort h) {
    return __uint_as_float(((unsigned)h) << 16);
}
__device__ __forceinline__ void gll16(const float4* g, float4* l) {
    __builtin_amdgcn_global_load_lds((const __attribute__((address_space(1))) void*)g,
                                     (__attribute__((address_space(3))) void*)l, 16, 0, 0);
}
// raw barrier (no vmcnt drain) with compiler memory fences on both sides
__device__ __forceinline__ void barrier_nd() {
    asm volatile("" ::: "memory");
    __builtin_amdgcn_s_barrier();
    asm volatile("" ::: "memory");
}
template <int N> __device__ __forceinline__ void waitVm() {
    if constexpr (N == 0) asm volatile("s_waitcnt vmcnt(0)" ::: "memory");
    else if constexpr (N == 1) asm volatile("s_waitcnt vmcnt(1)" ::: "memory");
    else asm volatile("s_waitcnt vmcnt(2)" ::: "memory");
}

// ---------------- kernel 0: fused transposes + weight prepack ----------------
__global__ __launch_bounds__(256) void k_prep(const float* __restrict__ x,
                                              const float* __restrict__ f,
                                              float4* __restrict__ xT4,
                                              ushort* __restrict__ fT,
                                              const float* __restrict__ w_att,
                                              const float* __restrict__ w_conv,
                                              const float* __restrict__ w_out,
                                              const float* __restrict__ w_mlp,
                                              const float* __restrict__ b_mlp,
                                              short8* __restrict__ wattF,
                                              short8* __restrict__ wconvF,
                                              short8* __restrict__ woutF,
                                              float* __restrict__ wmlp8) {
    int i = blockIdx.x * 256 + threadIdx.x;
    if (i < BATCH * NPTS) {
        int b = i / NPTS, n = i % NPTS;
        const float* xb = x + (size_t)b * 3 * NPTS;
        float x0 = xb[n], x1 = xb[NPTS + n], x2 = xb[2 * NPTS + n];
        float sq = fmaf(x2, x2, fmaf(x1, x1, x0 * x0));
        xT4[i] = make_float4(x0, x1, x2, sq);
    }
    if (i < BATCH * INC * NPTS) {
        int n = i % NPTS; int t = i / NPTS; int c = t % INC; int b = t / INC;
        fT[((size_t)(b * NPTS + n)) * INC + c] = f2bf(f[i]);
    }
    if (blockIdx.x == gridDim.x - 1) {
        int t = threadIdx.x;
        for (int idx = t; idx < 14 * 64; idx += 256) {
            int fr = idx >> 6, ln = idx & 63, l31 = ln & 31, h8 = (ln >> 5) * 8;
            short8 v;
            if (fr < 8) {
                int nt = fr >> 2, kt = fr & 3;
                const float* s = w_att + (nt * 32 + l31) * 64 + kt * 16 + h8;
#pragma unroll
                for (int j = 0; j < 8; ++j) v[j] = (short)f2bf(s[j]);
                wattF[fr * 64 + ln] = v;
            } else if (fr < 12) {
                int kt = fr - 8;
                const float* s = w_conv + l31 * 64 + kt * 16 + h8;
#pragma unroll
                for (int j = 0; j < 8; ++j) v[j] = (short)f2bf(s[j]);
                wconvF[kt * 64 + ln] = v;
            } else {
                int kt = fr - 12;
                const float* s = w_out + l31 * 32 + kt * 16 + h8;
#pragma unroll
                for (int j = 0; j < 8; ++j) v[j] = (short)f2bf(s[j]);
                woutF[kt * 64 + ln] = v;
            }
        }
        for (int idx = t; idx < 512; idx += 256) {
            int e = idx >> 3, j = idx & 7;
            wmlp8[idx] = (j < 7) ? w_mlp[e * 7 + j] : b_mlp[e];
        }
    }
}

// ---------------- kernel 1: FUSED knn + attention ----------------
// R16 = R13 exactly (best passing config, 84.5us) + one micro-fix:
// the pooling phase's readlane(mzl, j) had a LANE-DIVERGENT j (cr+4*hi)
// -> waterfall; replaced by two immediate-lane readlanes + select.
// (R15's register-sourced pooling regressed: ushort[24] arrays were
// demoted to scratch -> FETCH 5.3->45MB. Reverted.)
#define CAP   192
#define PPBK  8
#define FWSZ  (KNBR * 64)   // 1280 ushorts per wave
__global__ __launch_bounds__(512, 6) void k_fused(const float4* __restrict__ xT4,
                                                  const ushort* __restrict__ fbT,
                                                  const float* __restrict__ wmlp8,
                                                  const short8* __restrict__ wattF,
                                                  const short8* __restrict__ wconvF,
                                                  const short8* __restrict__ woutF,
                                                  float* __restrict__ out) {
    __shared__ __align__(16) char smA[36864];       // cand[3][512]f4(24K)+surv[8][192]u64(12K) / Fb 8x1280u16(20K)
    float4*             candB = (float4*)smA;
    unsigned long long* survB = (unsigned long long*)(smA + 24576);
    ushort*             FbB   = (ushort*)smA;
    __shared__ int scnt[PPBK], slot[PPBK];
    __shared__ int neighL[PPBK][KNBR];              // 640 B
    __shared__ __align__(16) ushort pool[PPBK][64]; // 1024 B

    const int tid  = threadIdx.x;
    const int lane = tid & 63;
    const int wv   = tid >> 6;
    const int hi   = lane >> 5;
    const int l31  = lane & 31;
    const int gp   = blockIdx.x * PPBK + wv;
    const int b    = gp >> 12;
    const int nb   = gp & (NPTS - 1);
    const float4* base = xT4 + (size_t)b * NPTS;

    if (lane == 0) { scnt[wv] = 0; slot[wv] = 1; }

    float4 me = xT4[gp];
    asm volatile("s_waitcnt vmcnt(0)" ::: "memory");   // me landed; vmcnt now counts only gll16s

    auto stage = [&](int c) {
        const float4* src = base + c * 512 + wv * 64 + lane;
        float4* dst = candB + (c % 3) * 512 + wv * 64;   // wave-uniform base; HW adds lane*16
        gll16(src, dst);
    };
    auto dist = [&](const float4& o) -> unsigned {
        float dot = fmaf(o.z, me.z, fmaf(o.y, me.y, o.x * me.x));
        return __float_as_uint(fmaxf((me.w + o.w) - 2.0f * dot, 0.0f));
    };

    stage(0); stage(1); stage(2);

    // ---- phase A1: chunks 0,1 -> bits[16] + per-lane min/2nd-min ----
    unsigned bits[16];
    unsigned lmin = 0xFFFFFFFFu, lmin2 = 0xFFFFFFFFu;

    waitVm<2>(); barrier_nd();                 // chunk 0 resident everywhere
#pragma unroll
    for (int j = 0; j < 8; ++j) {
        unsigned bb = dist(candB[lane + 64 * j]);
        bits[j] = bb;
        unsigned lo_ = bb < lmin ? bb : lmin;
        unsigned hi_ = bb < lmin ? lmin : bb;
        lmin = lo_;
        lmin2 = hi_ < lmin2 ? hi_ : lmin2;
    }
    barrier_nd(); stage(3);                    // buf0 reads retired -> chunk 3 may land

    waitVm<2>(); barrier_nd();                 // chunk 1 resident
#pragma unroll
    for (int j = 0; j < 8; ++j) {
        unsigned bb = dist(candB[512 + lane + 64 * j]);
        bits[8 + j] = bb;
        unsigned lo_ = bb < lmin ? bb : lmin;
        unsigned hi_ = bb < lmin ? lmin : bb;
        lmin = lo_;
        lmin2 = hi_ < lmin2 ? hi_ : lmin2;
    }
    barrier_nd(); stage(4);                    // buf1 retired -> chunk 4

    // tau bisect: count candidates capped at 2/lane (valid upper bound).
    unsigned lo = 0u, hi2 = 0xFF000000u;
    for (int it = 0; it < 16 && lo < hi2; ++it) {
        unsigned mid = lo + ((hi2 - lo) >> 1);
        int c = __popcll(__ballot(lmin <= mid)) + __popcll(__ballot(lmin2 <= mid));
        if (c >= KNBR) hi2 = mid; else lo = mid + 1;
    }
    const unsigned tau = hi2;

    // subset append (surv/scnt per-wave: no cross-wave hazard)
#pragma unroll
    for (int j = 0; j < 16; ++j) {
        if (bits[j] <= tau) {
            int pos = atomicAdd(&scnt[wv], 1);
            if (pos < CAP)
                survB[wv * CAP + pos] = ((unsigned long long)bits[j] << 32) | (unsigned)(lane + 64 * j);
        }
    }

    // ---- phase A2: chunks 2..7, pipelined ----
#pragma unroll
    for (int ch = 2; ch < 8; ++ch) {
        if (ch <= 5) waitVm<2>(); else if (ch == 6) waitVm<1>(); else waitVm<0>();
        barrier_nd();                          // chunk ch resident everywhere
        const float4* cb = candB + (ch % 3) * 512;
        const int ib = ch * 512 + lane;
#pragma unroll
        for (int j = 0; j < 8; ++j) {
            unsigned bb = dist(cb[lane + 64 * j]);
            if (bb <= tau) {
                int pos = atomicAdd(&scnt[wv], 1);
                if (pos < CAP)
                    survB[wv * CAP + pos] = ((unsigned long long)bb << 32) | (unsigned)(ib + 64 * j);
            }
        }
        barrier_nd();                          // buf ch%3 reads retired
        if (ch < 5) stage(ch + 3);             // chunk ch+3 -> buf ch%3
    }

    // ---- phase A3: exact top-20 set ----
    int cnt = scnt[wv]; if (cnt > CAP) cnt = CAP;
    const unsigned long long* sv = survB + wv * CAP;

    if (cnt <= 128) {   // common path: 2 keys/lane
        unsigned long long k0 = (lane      < cnt) ? sv[lane     ] : ~0ull;
        unsigned long long k1 = (lane + 64 < cnt) ? sv[lane + 64] : ~0ull;
        unsigned d0 = (unsigned)(k0 >> 32), d1 = (unsigned)(k1 >> 32);
        unsigned i0 = (unsigned)k0, i1 = (unsigned)k1;

        unsigned th;
        {
            unsigned l2 = 0u, h2 = tau;
            bool found = false;
            for (int it = 0; it < 32; ++it) {
                unsigned mid = l2 + ((h2 - l2) >> 1);
                int c = __popcll(__ballot(d0 <= mid)) + __popcll(__ballot(d1 <= mid));
                if (c >= KNBR) h2 = mid; else l2 = mid + 1;
                if (c == KNBR) {              // exact: 20th = max key <= mid
                    unsigned mm = (d0 <= mid) ? d0 : 0u;
                    unsigned m2_ = (d1 <= mid) ? d1 : 0u;
                    mm = mm > m2_ ? mm : m2_;
#pragma unroll
                    for (int off = 32; off >= 1; off >>= 1) {
                        unsigned o = __shfl_xor(mm, off, 64);
                        mm = o > mm ? o : mm;
                    }
                    th = mm; found = true; break;
                }
                if (l2 >= h2) break;
            }
            if (!found) th = h2;
        }
        int cless = __popcll(__ballot(d0 < th)) + __popcll(__ballot(d1 < th));
        int need = KNBR - cless;
        bool t0 = (d0 == th), t1 = (d1 == th);
        int tcnt = __popcll(__ballot(t0)) + __popcll(__ballot(t1));
        unsigned idxthr = 0xFFFFFFFFu;
        if (tcnt != need) {       // rare exact-d2-tie path (uniform branch)
            unsigned la = 0u, ha = 0xFFFFFFFFu;
            for (int it = 0; it < 32; ++it) {
                unsigned mid = la + ((ha - la) >> 1);
                int c = __popcll(__ballot(t0 && i0 <= mid)) + __popcll(__ballot(t1 && i1 <= mid));
                if (c >= need) ha = mid; else la = mid + 1;
            }
            idxthr = ha;
        }
        bool s0 = (d0 < th) || (t0 && i0 <= idxthr);
        bool s1 = (d1 < th) || (t1 && i1 <= idxthr);

        unsigned long long mk = k0 < k1 ? k0 : k1;
#pragma unroll
        for (int off = 32; off >= 1; off >>= 1) {
            unsigned long long o = __shfl_xor(mk, off, 64);
            mk = o < mk ? o : mk;
        }
        if (s0) { if (k0 == mk) neighL[wv][0] = (int)i0; else { int p = atomicAdd(&slot[wv], 1); neighL[wv][p] = (int)i0; } }
        if (s1) { if (k1 == mk) neighL[wv][0] = (int)i1; else { int p = atomicAdd(&slot[wv], 1); neighL[wv][p] = (int)i1; } }
    } else {            // rare fallback: 3 keys/lane (cnt <= 192 by CAP)
        unsigned long long k0 = (lane       < cnt) ? sv[lane      ] : ~0ull;
        unsigned long long k1 = (lane +  64 < cnt) ? sv[lane +  64] : ~0ull;
        unsigned long long k2 = (lane + 128 < cnt) ? sv[lane + 128] : ~0ull;
        unsigned d0 = (unsigned)(k0 >> 32), d1 = (unsigned)(k1 >> 32), d2 = (unsigned)(k2 >> 32);
        unsigned i0 = (unsigned)k0, i1 = (unsigned)k1, i2 = (unsigned)k2;

        unsigned l2 = 0u, h2 = tau;
        for (int it = 0; it < 32 && l2 < h2; ++it) {
            unsigned mid = l2 + ((h2 - l2) >> 1);
            int c = __popcll(__ballot(d0 <= mid)) + __popcll(__ballot(d1 <= mid))
                  + __popcll(__ballot(d2 <= mid));
            if (c >= KNBR) h2 = mid; else l2 = mid + 1;
        }
        const unsigned th = h2;
        int cless = __popcll(__ballot(d0 < th)) + __popcll(__ballot(d1 < th))
                  + __popcll(__ballot(d2 < th));
        int need = KNBR - cless;
        bool t0 = (d0 == th), t1 = (d1 == th), t2 = (d2 == th);
        int tcnt = __popcll(__ballot(t0)) + __popcll(__ballot(t1)) + __popcll(__ballot(t2));
        unsigned idxthr = 0xFFFFFFFFu;
        if (tcnt != need) {
            unsigned la = 0u, ha = 0xFFFFFFFFu;
            for (int it = 0; it < 32; ++it) {
                unsigned mid = la + ((ha - la) >> 1);
                int c = __popcll(__ballot(t0 && i0 <= mid)) + __popcll(__ballot(t1 && i1 <= mid))
                      + __popcll(__ballot(t2 && i2 <= mid));
                if (c >= need) ha = mid; else la = mid + 1;
            }
            idxthr = ha;
        }
        bool s0 = (d0 < th) || (t0 && i0 <= idxthr);
        bool s1 = (d1 < th) || (t1 && i1 <= idxthr);
        bool s2 = (d2 < th) || (t2 && i2 <= idxthr);

        unsigned long long m01 = k0 < k1 ? k0 : k1;
        unsigned long long mk  = m01 < k2 ? m01 : k2;
#pragma unroll
        for (int off = 32; off >= 1; off >>= 1) {
            unsigned long long o = __shfl_xor(mk, off, 64);
            mk = o < mk ? o : mk;
        }
        if (s0) { if (k0 == mk) neighL[wv][0] = (int)i0; else { int p = atomicAdd(&slot[wv], 1); neighL[wv][p] = (int)i0; } }
        if (s1) { if (k1 == mk) neighL[wv][0] = (int)i1; else { int p = atomicAdd(&slot[wv], 1); neighL[wv][p] = (int)i1; } }
        if (s2) { if (k2 == mk) neighL[wv][0] = (int)i2; else { int p = atomicAdd(&slot[wv], 1); neighL[wv][p] = (int)i2; } }
    }

    __syncthreads();   // Fb (aliased over cand+surv) written below; full drain OK here

    // ================= phase B: attention =================
    const ushort* fb = fbT + (size_t)b * NPTS * INC;
    ushort* Fw = FbB + wv * FWSZ;

    int nv = 0;
    if (l31 < KNBR) nv = neighL[wv][l31];
    float4 ncl = base[nv];

    float wm[8];
    {
        const float4* w8 = (const float4*)(wmlp8 + l31 * 8);
        float4 a = w8[0], bq = w8[1];
        wm[0] = a.x; wm[1] = a.y; wm[2] = a.z; wm[3] = a.w;
        wm[4] = bq.x; wm[5] = bq.y; wm[6] = bq.z; wm[7] = bq.w;
    }
    const float c0x = rlf(ncl.x, 0), c0y = rlf(ncl.y, 0), c0z = rlf(ncl.z, 0);

    // batched gather prefetch: all 20 feature loads issued before any use
    ushort fr[KNBR];
#pragma unroll
    for (int k = 0; k < KNBR; ++k) {
        int snk = __builtin_amdgcn_readlane(nv, k);
        fr[k] = fb[(size_t)snk * INC + l31];
    }

    // per-lane relative coords (lane k owns neighbor k); consumed via readlane
    float rxl = ncl.x - c0x, ryl = ncl.y - c0y, rzl = ncl.z - c0z;
    float disl = sqrtf(fmaf(rzl, rzl, fmaf(ryl, ryl, rxl * rxl)));

    float fmbase = wm[7];
    fmbase = fmaf(wm[0], c0x, fmbase); fmbase = fmaf(wm[1], c0y, fmbase);
    fmbase = fmaf(wm[2], c0z, fmbase);
#pragma unroll
    for (int k = 0; k < KNBR; ++k) {
        float fm = fmbase;
        fm = fmaf(wm[3], rlf(rxl, k), fm);
        fm = fmaf(wm[4], rlf(ryl, k), fm);
        fm = fmaf(wm[5], rlf(rzl, k), fm);
        fm = fmaf(wm[6], rlf(disl, k), fm);
        ushort fbits = hi ? f2bf(fm) : fr[k];
        Fw[k * 64 + (lane ^ ((k & 7) << 3))] = fbits;
    }

    const int rowA = (l31 < KNBR) ? l31 : (KNBR - 1);   // rows 20..31 = row-19 copies
    short8 Af[4];
#pragma unroll
    for (int kt = 0; kt < 4; ++kt) {
        int c0 = kt * 16 + 8 * hi;
        Af[kt] = *(const short8*)&Fw[rowA * 64 + (c0 ^ ((rowA & 7) << 3))];
    }

    // flipped orientation: lane k holds d-column -> lane-local softmax stats
    float mloc, zloc;
    {
        f32x16 af;
#pragma unroll
        for (int i = 0; i < 16; ++i) af[i] = 0.f;
        __builtin_amdgcn_s_setprio(1);
#pragma unroll
        for (int kt = 0; kt < 4; ++kt)
            af = __builtin_amdgcn_mfma_f32_32x32x16_bf16(wattF[kt * 64 + lane], Af[kt], af, 0, 0, 0);
        __builtin_amdgcn_s_setprio(0);
        float m0 = af[0];
#pragma unroll
        for (int i = 1; i < 16; ++i) m0 = fmaxf(m0, af[i]);
        float z0 = 0.f;
#pragma unroll
        for (int i = 0; i < 16; ++i) z0 += __expf(af[i] - m0);
        mloc = m0; zloc = z0;
    }
    {
        f32x16 af;
#pragma unroll
        for (int i = 0; i < 16; ++i) af[i] = 0.f;
        __builtin_amdgcn_s_setprio(1);
#pragma unroll
        for (int kt = 0; kt < 4; ++kt)
            af = __builtin_amdgcn_mfma_f32_32x32x16_bf16(wattF[(4 + kt) * 64 + lane], Af[kt], af, 0, 0, 0);
        __builtin_amdgcn_s_setprio(0);
        float m1 = af[0];
#pragma unroll
        for (int i = 1; i < 16; ++i) m1 = fmaxf(m1, af[i]);
        float z1 = 0.f;
#pragma unroll
        for (int i = 0; i < 16; ++i) z1 += __expf(af[i] - m1);
        float mn = fmaxf(mloc, m1);
        zloc = zloc * __expf(mloc - mn) + z1 * __expf(m1 - mn);
        mloc = mn;
    }
    float mo = fmaxf(mloc, __shfl_xor(mloc, 32, 64));
    float zs = zloc * __expf(mloc - mo);
    float Zk = zs + __shfl_xor(zs, 32, 64);
    float mzl = mo + __logf(Zk);      // log-fold: attn = exp(s - mzl)
    // stats for neighbor j live in lane j (and j+32): immediate-lane readlanes + select

    // original orientation + pooling, half at a time
    float pooled0 = 0.f, pooled1 = 0.f;
    {
        f32x16 acc;
#pragma unroll
        for (int i = 0; i < 16; ++i) acc[i] = 0.f;
        __builtin_amdgcn_s_setprio(1);
#pragma unroll
        for (int kt = 0; kt < 4; ++kt)
            acc = __builtin_amdgcn_mfma_f32_32x32x16_bf16(Af[kt], wattF[kt * 64 + lane], acc, 0, 0, 0);
        __builtin_amdgcn_s_setprio(0);
#pragma unroll
        for (int r = 0; r < 12; ++r) {
            const int cr = (r & 3) + 8 * (r >> 2);          // j = cr + 4*hi
            const int j = cr + 4 * hi;
            float mzj = hi ? rlf(mzl, cr + 4) : rlf(mzl, cr);   // immediate lanes, no waterfall
            float a0 = __expf(acc[r] - mzj);
            float f0 = bf2f(Fw[j * 64 + (l31 ^ ((j & 7) << 3))]);
            float p0 = a0 * f0;
            if (r >= 8) p0 = hi ? 0.f : p0;           // j>=20 rows invalid
            pooled0 += p0;
        }
    }
    {
        f32x16 acc;
#pragma unroll
        for (int i = 0; i < 16; ++i) acc[i] = 0.f;
        __builtin_amdgcn_s_setprio(1);
#pragma unroll
        for (int kt = 0; kt < 4; ++kt)
            acc = __builtin_amdgcn_mfma_f32_32x32x16_bf16(Af[kt], wattF[(4 + kt) * 64 + lane], acc, 0, 0, 0);
        __builtin_amdgcn_s_setprio(0);
#pragma unroll
        for (int r = 0; r < 12; ++r) {
            const int cr = (r & 3) + 8 * (r >> 2);
            const int j = cr + 4 * hi;
            float mzj = hi ? rlf(mzl, cr + 4) : rlf(mzl, cr);
            float a1 = __expf(acc[r] - mzj);
            float f1 = bf2f(Fw[j * 64 + ((32 + l31) ^ ((j & 7) << 3))]);
            float p1 = a1 * f1;
            if (r >= 8) p1 = hi ? 0.f : p1;
            pooled1 += p1;
        }
    }
    pooled0 += __shfl_xor(pooled0, 32, 64);
    pooled1 += __shfl_xor(pooled1, 32, 64);
    if (!hi) {
        pool[wv][l31]      = f2bf(pooled0);
        pool[wv][32 + l31] = f2bf(pooled1);
    }

    // epilogue: out = W_conv@pooled + W_out@feat (biases cancel in BN)
    f32x16 oa;
#pragma unroll
    for (int i = 0; i < 16; ++i) oa[i] = 0.f;
    __builtin_amdgcn_s_setprio(1);
#pragma unroll
    for (int kt = 0; kt < 4; ++kt) {
        short8 bb = *(const short8*)&pool[wv][kt * 16 + 8 * hi];
        oa = __builtin_amdgcn_mfma_f32_32x32x16_bf16(wconvF[kt * 64 + lane], bb, oa, 0, 0, 0);
    }
#pragma unroll
    for (int kt = 0; kt < 2; ++kt) {
        short8 bb = *(const short8*)(fb + (size_t)nb * INC + kt * 16 + 8 * hi);
        oa = __builtin_amdgcn_mfma_f32_32x32x16_bf16(woutF[kt * 64 + lane], bb, oa, 0, 0, 0);
    }
    __builtin_amdgcn_s_setprio(0);
#pragma unroll
    for (int r = 0; r < 16; ++r) {
        int o = (r & 3) + 8 * (r >> 2) + 4 * hi;
        if (l31 == 0) out[((size_t)(b * OUTC + o)) * NPTS + nb] = oa[r];
    }
}

// ---------------- kernel 2: fused BatchNorm (stats + normalize) ----------------
__global__ __launch_bounds__(256) void k_bn(float* __restrict__ of,
                                            const float* __restrict__ gamma,
                                            const float* __restrict__ beta) {
    const int c = blockIdx.x;
    const int tid = threadIdx.x;
    float s = 0.f, s2 = 0.f;
#pragma unroll
    for (int b = 0; b < BATCH; ++b) {
        const float4* p = (const float4*)(of + ((size_t)b * OUTC + c) * NPTS);
        for (int i = tid; i < NPTS / 4; i += 256) {
            float4 v = p[i];
            s += (v.x + v.y) + (v.z + v.w);
            s2 = fmaf(v.x, v.x, s2); s2 = fmaf(v.y, v.y, s2);
            s2 = fmaf(v.z, v.z, s2); s2 = fmaf(v.w, v.w, s2);
        }
    }
#pragma unroll
    for (int off = 32; off >= 1; off >>= 1) {
        s += __shfl_xor(s, off, 64);
        s2 += __shfl_xor(s2, off, 64);
    }
    __shared__ float rs[4], rs2[4];
    __shared__ float sc[2];
    if ((tid & 63) == 0) { rs[tid >> 6] = s; rs2[tid >> 6] = s2; }
    __syncthreads();
    if (tid == 0) {
        float S = (rs[0] + rs[1]) + (rs[2] + rs[3]);
        float S2 = (rs2[0] + rs2[1]) + (rs2[2] + rs2[3]);
        const float invn = 1.0f / (BATCH * NPTS);
        float mean = S * invn;
        float var = S2 * invn - mean * mean;
        float rstd = rsqrtf(var + EPSBN);
        float scale = rstd * gamma[c];
        sc[0] = scale;
        sc[1] = beta[c] - mean * scale;
    }
    __syncthreads();
    const float scale = sc[0], shift = sc[1];
#pragma unroll
    for (int b = 0; b < BATCH; ++b) {
        float4* p = (float4*)(of + ((size_t)b * OUTC + c) * NPTS);
        for (int i = tid; i < NPTS / 4; i += 256) {
            float4 v = p[i];
            v.x = fmaf(v.x, scale, shift);
            v.y = fmaf(v.y, scale, shift);
            v.z = fmaf(v.z, scale, shift);
            v.w = fmaf(v.w, scale, shift);
            p[i] = v;
        }
    }
}

// ---------------- launch ----------------
extern "C" void kernel_launch(void* const* d_in, const int* in_sizes, int n_in,
                              void* d_out, int out_size, void* d_ws, size_t ws_size,
                              hipStream_t stream) {
    const float* x      = (const float*)d_in[0];
    const float* feat   = (const float*)d_in[1];
    const float* w_mlp  = (const float*)d_in[2];
    const float* b_mlp  = (const float*)d_in[3];
    const float* w_att  = (const float*)d_in[4];
    const float* w_conv = (const float*)d_in[5];
    const float* w_out  = (const float*)d_in[7];
    const float* gamma  = (const float*)d_in[9];
    const float* beta   = (const float*)d_in[10];
    float* out = (float*)d_out;

    char* ws = (char*)d_ws;
    float4* xT4    = (float4*)ws;                          // 262144 B
    ushort* fbT    = (ushort*)(ws + 262144);               // 1048576 B
    short8* wattF  = (short8*)(ws + 1310976);              // 8192 B
    short8* wconvF = (short8*)(ws + 1319168);              // 4096 B
    short8* woutF  = (short8*)(ws + 1323264);              // 2048 B
    float*  wmlp8  = (float*)(ws + 1325312);               // 2048 B

    k_prep<<<(BATCH * INC * NPTS + 255) / 256 + 1, 256, 0, stream>>>(
        x, feat, xT4, fbT, w_att, w_conv, w_out, w_mlp, b_mlp,
        wattF, wconvF, woutF, wmlp8);
    k_fused<<<(BATCH * NPTS) / PPBK, 512, 0, stream>>>(xT4, fbT, wmlp8,
                                                       wattF, wconvF, woutF, out);
    k_bn<<<OUTC, 256, 0, stream>>>(out, gamma, beta);
}

// Round 17
// 84.495 us; speedup vs baseline: 1.3335x; 1.3335x over previous
//
#include <hip/hip_runtime.h>
#include <hip/hip_bf16.h>

#define BATCH 4
#define NPTS  4096
#define KNBR  20
#define INC   32
#define TWC   64   // 2*INC
#define OUTC  32
#define EPSBN 1e-5f

typedef short short8 __attribute__((ext_vector_type(8)));
typedef float f32x16 __attribute__((ext_vector_type(16)));

// ---------------- helpers ----------------
__device__ __forceinline__ float rlf(float v, int l) {
    return __uint_as_float((unsigned)__builtin_amdgcn_readlane((int)__float_as_uint(v), l));
}
__device__ __forceinline__ ushort f2bf(float x) {        // fp32 -> bf16 bits (RNE)
    unsigned u = __float_as_uint(x);
    unsigned r = u + 0x7FFFu + ((u >> 16) & 1u);
    return (ushort)(r >> 16);
}
__device__ __forceinline__ float bf2f(ushort h) {
    return __uint_as_float(((unsigned)h) << 16);
}
__device__ __forceinline__ void gll16(const float4* g, float4* l) {
    __builtin_amdgcn_global_load_lds((const __attribute__((address_space(1))) void*)g,
                                     (__attribute__((address_space(3))) void*)l, 16, 0, 0);
}
// raw barrier (no vmcnt drain) with compiler memory fences on both sides
__device__ __forceinline__ void barrier_nd() {
    asm volatile("" ::: "memory");
    __builtin_amdgcn_s_barrier();
    asm volatile("" ::: "memory");
}
template <int N> __device__ __forceinline__ void waitVm() {
    if constexpr (N == 0) asm volatile("s_waitcnt vmcnt(0)" ::: "memory");
    else if constexpr (N == 1) asm volatile("s_waitcnt vmcnt(1)" ::: "memory");
    else asm volatile("s_waitcnt vmcnt(2)" ::: "memory");
}

// ---------------- kernel 0: fused transposes + weight prepack ----------------
__global__ __launch_bounds__(256) void k_prep(const float* __restrict__ x,
                                              const float* __restrict__ f,
                                              float4* __restrict__ xT4,
                                              ushort* __restrict__ fT,
                                              const float* __restrict__ w_att,
                                              const float* __restrict__ w_conv,
                                              const float* __restrict__ w_out,
                                              const float* __restrict__ w_mlp,
                                              const float* __restrict__ b_mlp,
                                              short8* __restrict__ wattF,
                                              short8* __restrict__ wconvF,
                                              short8* __restrict__ woutF,
                                              float* __restrict__ wmlp8) {
    int i = blockIdx.x * 256 + threadIdx.x;
    if (i < BATCH * NPTS) {
        int b = i / NPTS, n = i % NPTS;
        const float* xb = x + (size_t)b * 3 * NPTS;
        float x0 = xb[n], x1 = xb[NPTS + n], x2 = xb[2 * NPTS + n];
        float sq = fmaf(x2, x2, fmaf(x1, x1, x0 * x0));
        xT4[i] = make_float4(x0, x1, x2, sq);
    }
    if (i < BATCH * INC * NPTS) {
        int n = i % NPTS; int t = i / NPTS; int c = t % INC; int b = t / INC;
        fT[((size_t)(b * NPTS + n)) * INC + c] = f2bf(f[i]);
    }
    if (blockIdx.x == gridDim.x - 1) {
        int t = threadIdx.x;
        for (int idx = t; idx < 14 * 64; idx += 256) {
            int fr = idx >> 6, ln = idx & 63, l31 = ln & 31, h8 = (ln >> 5) * 8;
            short8 v;
            if (fr < 8) {
                int nt = fr >> 2, kt = fr & 3;
                const float* s = w_att + (nt * 32 + l31) * 64 + kt * 16 + h8;
#pragma unroll
                for (int j = 0; j < 8; ++j) v[j] = (short)f2bf(s[j]);
                wattF[fr * 64 + ln] = v;
            } else if (fr < 12) {
                int kt = fr - 8;
                const float* s = w_conv + l31 * 64 + kt * 16 + h8;
#pragma unroll
                for (int j = 0; j < 8; ++j) v[j] = (short)f2bf(s[j]);
                wconvF[kt * 64 + ln] = v;
            } else {
                int kt = fr - 12;
                const float* s = w_out + l31 * 32 + kt * 16 + h8;
#pragma unroll
                for (int j = 0; j < 8; ++j) v[j] = (short)f2bf(s[j]);
                woutF[kt * 64 + ln] = v;
            }
        }
        for (int idx = t; idx < 512; idx += 256) {
            int e = idx >> 3, j = idx & 7;
            wmlp8[idx] = (j < 7) ? w_mlp[e * 7 + j] : b_mlp[e];
        }
    }
}

// ---------------- kernel 1: FUSED knn + attention ----------------
// 512 threads = 8 waves = 8 points. Phase A: filter+exact-set KNN with a
// TRIPLE-BUFFERED staging pipeline (counted vmcnt + raw s_barrier; never
// vmcnt(0) in the chunk loop). Issue ledger per wave: 3 prologue stages +
// stage(ch+3) at end of iters 0..4 = 8 total; before reading chunk ch,
// outstanding = issued-(ch+1) = 2 (ch<=5), 1 (ch=6), 0 (ch=7).
// Phase B: dual-orientation MFMA attention.
// This is the R13 kernel verbatim -- the empirically best configuration
// (84.5us total). R14 (x-prefilter), R15 (register-sourced pooling), and
// R16 (immediate-readlane select) all regressed: the first by adding
// non-wave-uniform filter work, the latter two by tripping register-
// allocator cliffs (ushort arrays -> scratch; extra live values -> spill).
// LDS: cand 24K + surv 12K = 36K, Fb(20K) aliases; total ~38.6K -> 4
// blocks/CU = 32 waves/CU cap. CAP=192 (R11's 128 overflowed).
#define CAP   192
#define PPBK  8
#define FWSZ  (KNBR * 64)   // 1280 ushorts per wave
__global__ __launch_bounds__(512, 6) void k_fused(const float4* __restrict__ xT4,
                                                  const ushort* __restrict__ fbT,
                                                  const float* __restrict__ wmlp8,
                                                  const short8* __restrict__ wattF,
                                                  const short8* __restrict__ wconvF,
                                                  const short8* __restrict__ woutF,
                                                  float* __restrict__ out) {
    __shared__ __align__(16) char smA[36864];       // cand[3][512]f4(24K)+surv[8][192]u64(12K) / Fb 8x1280u16(20K)
    float4*             candB = (float4*)smA;
    unsigned long long* survB = (unsigned long long*)(smA + 24576);
    ushort*             FbB   = (ushort*)smA;
    __shared__ int scnt[PPBK], slot[PPBK];
    __shared__ int neighL[PPBK][KNBR];              // 640 B
    __shared__ __align__(16) ushort pool[PPBK][64]; // 1024 B

    const int tid  = threadIdx.x;
    const int lane = tid & 63;
    const int wv   = tid >> 6;
    const int hi   = lane >> 5;
    const int l31  = lane & 31;
    const int gp   = blockIdx.x * PPBK + wv;
    const int b    = gp >> 12;
    const int nb   = gp & (NPTS - 1);
    const float4* base = xT4 + (size_t)b * NPTS;

    if (lane == 0) { scnt[wv] = 0; slot[wv] = 1; }

    float4 me = xT4[gp];
    asm volatile("s_waitcnt vmcnt(0)" ::: "memory");   // me landed; vmcnt now counts only gll16s

    auto stage = [&](int c) {
        const float4* src = base + c * 512 + wv * 64 + lane;
        float4* dst = candB + (c % 3) * 512 + wv * 64;   // wave-uniform base; HW adds lane*16
        gll16(src, dst);
    };
    auto dist = [&](const float4& o) -> unsigned {
        float dot = fmaf(o.z, me.z, fmaf(o.y, me.y, o.x * me.x));
        return __float_as_uint(fmaxf((me.w + o.w) - 2.0f * dot, 0.0f));
    };

    stage(0); stage(1); stage(2);

    // ---- phase A1: chunks 0,1 -> bits[16] + per-lane min/2nd-min ----
    unsigned bits[16];
    unsigned lmin = 0xFFFFFFFFu, lmin2 = 0xFFFFFFFFu;

    waitVm<2>(); barrier_nd();                 // chunk 0 resident everywhere
#pragma unroll
    for (int j = 0; j < 8; ++j) {
        unsigned bb = dist(candB[lane + 64 * j]);
        bits[j] = bb;
        unsigned lo_ = bb < lmin ? bb : lmin;
        unsigned hi_ = bb < lmin ? lmin : bb;
        lmin = lo_;
        lmin2 = hi_ < lmin2 ? hi_ : lmin2;
    }
    barrier_nd(); stage(3);                    // buf0 reads retired -> chunk 3 may land

    waitVm<2>(); barrier_nd();                 // chunk 1 resident
#pragma unroll
    for (int j = 0; j < 8; ++j) {
        unsigned bb = dist(candB[512 + lane + 64 * j]);
        bits[8 + j] = bb;
        unsigned lo_ = bb < lmin ? bb : lmin;
        unsigned hi_ = bb < lmin ? lmin : bb;
        lmin = lo_;
        lmin2 = hi_ < lmin2 ? hi_ : lmin2;
    }
    barrier_nd(); stage(4);                    // buf1 retired -> chunk 4

    // tau bisect: count candidates capped at 2/lane (valid upper bound).
    unsigned lo = 0u, hi2 = 0xFF000000u;
    for (int it = 0; it < 16 && lo < hi2; ++it) {
        unsigned mid = lo + ((hi2 - lo) >> 1);
        int c = __popcll(__ballot(lmin <= mid)) + __popcll(__ballot(lmin2 <= mid));
        if (c >= KNBR) hi2 = mid; else lo = mid + 1;
    }
    const unsigned tau = hi2;

    // subset append (surv/scnt per-wave: no cross-wave hazard)
#pragma unroll
    for (int j = 0; j < 16; ++j) {
        if (bits[j] <= tau) {
            int pos = atomicAdd(&scnt[wv], 1);
            if (pos < CAP)
                survB[wv * CAP + pos] = ((unsigned long long)bits[j] << 32) | (unsigned)(lane + 64 * j);
        }
    }

    // ---- phase A2: chunks 2..7, pipelined ----
#pragma unroll
    for (int ch = 2; ch < 8; ++ch) {
        if (ch <= 5) waitVm<2>(); else if (ch == 6) waitVm<1>(); else waitVm<0>();
        barrier_nd();                          // chunk ch resident everywhere
        const float4* cb = candB + (ch % 3) * 512;
        const int ib = ch * 512 + lane;
#pragma unroll
        for (int j = 0; j < 8; ++j) {
            unsigned bb = dist(cb[lane + 64 * j]);
            if (bb <= tau) {
                int pos = atomicAdd(&scnt[wv], 1);
                if (pos < CAP)
                    survB[wv * CAP + pos] = ((unsigned long long)bb << 32) | (unsigned)(ib + 64 * j);
            }
        }
        barrier_nd();                          // buf ch%3 reads retired
        if (ch < 5) stage(ch + 3);             // chunk ch+3 -> buf ch%3
    }

    // ---- phase A3: exact top-20 set ----
    int cnt = scnt[wv]; if (cnt > CAP) cnt = CAP;
    const unsigned long long* sv = survB + wv * CAP;

    if (cnt <= 128) {   // common path: 2 keys/lane
        unsigned long long k0 = (lane      < cnt) ? sv[lane     ] : ~0ull;
        unsigned long long k1 = (lane + 64 < cnt) ? sv[lane + 64] : ~0ull;
        unsigned d0 = (unsigned)(k0 >> 32), d1 = (unsigned)(k1 >> 32);
        unsigned i0 = (unsigned)k0, i1 = (unsigned)k1;

        unsigned th;
        {
            unsigned l2 = 0u, h2 = tau;
            bool found = false;
            for (int it = 0; it < 32; ++it) {
                unsigned mid = l2 + ((h2 - l2) >> 1);
                int c = __popcll(__ballot(d0 <= mid)) + __popcll(__ballot(d1 <= mid));
                if (c >= KNBR) h2 = mid; else l2 = mid + 1;
                if (c == KNBR) {              // exact: 20th = max key <= mid
                    unsigned mm = (d0 <= mid) ? d0 : 0u;
                    unsigned m2_ = (d1 <= mid) ? d1 : 0u;
                    mm = mm > m2_ ? mm : m2_;
#pragma unroll
                    for (int off = 32; off >= 1; off >>= 1) {
                        unsigned o = __shfl_xor(mm, off, 64);
                        mm = o > mm ? o : mm;
                    }
                    th = mm; found = true; break;
                }
                if (l2 >= h2) break;
            }
            if (!found) th = h2;
        }
        int cless = __popcll(__ballot(d0 < th)) + __popcll(__ballot(d1 < th));
        int need = KNBR - cless;
        bool t0 = (d0 == th), t1 = (d1 == th);
        int tcnt = __popcll(__ballot(t0)) + __popcll(__ballot(t1));
        unsigned idxthr = 0xFFFFFFFFu;
        if (tcnt != need) {       // rare exact-d2-tie path (uniform branch)
            unsigned la = 0u, ha = 0xFFFFFFFFu;
            for (int it = 0; it < 32; ++it) {
                unsigned mid = la + ((ha - la) >> 1);
                int c = __popcll(__ballot(t0 && i0 <= mid)) + __popcll(__ballot(t1 && i1 <= mid));
                if (c >= need) ha = mid; else la = mid + 1;
            }
            idxthr = ha;
        }
        bool s0 = (d0 < th) || (t0 && i0 <= idxthr);
        bool s1 = (d1 < th) || (t1 && i1 <= idxthr);

        unsigned long long mk = k0 < k1 ? k0 : k1;
#pragma unroll
        for (int off = 32; off >= 1; off >>= 1) {
            unsigned long long o = __shfl_xor(mk, off, 64);
            mk = o < mk ? o : mk;
        }
        if (s0) { if (k0 == mk) neighL[wv][0] = (int)i0; else { int p = atomicAdd(&slot[wv], 1); neighL[wv][p] = (int)i0; } }
        if (s1) { if (k1 == mk) neighL[wv][0] = (int)i1; else { int p = atomicAdd(&slot[wv], 1); neighL[wv][p] = (int)i1; } }
    } else {            // rare fallback: 3 keys/lane (cnt <= 192 by CAP)
        unsigned long long k0 = (lane       < cnt) ? sv[lane      ] : ~0ull;
        unsigned long long k1 = (lane +  64 < cnt) ? sv[lane +  64] : ~0ull;
        unsigned long long k2 = (lane + 128 < cnt) ? sv[lane + 128] : ~0ull;
        unsigned d0 = (unsigned)(k0 >> 32), d1 = (unsigned)(k1 >> 32), d2 = (unsigned)(k2 >> 32);
        unsigned i0 = (unsigned)k0, i1 = (unsigned)k1, i2 = (unsigned)k2;

        unsigned l2 = 0u, h2 = tau;
        for (int it = 0; it < 32 && l2 < h2; ++it) {
            unsigned mid = l2 + ((h2 - l2) >> 1);
            int c = __popcll(__ballot(d0 <= mid)) + __popcll(__ballot(d1 <= mid))
                  + __popcll(__ballot(d2 <= mid));
            if (c >= KNBR) h2 = mid; else l2 = mid + 1;
        }
        const unsigned th = h2;
        int cless = __popcll(__ballot(d0 < th)) + __popcll(__ballot(d1 < th))
                  + __popcll(__ballot(d2 < th));
        int need = KNBR - cless;
        bool t0 = (d0 == th), t1 = (d1 == th), t2 = (d2 == th);
        int tcnt = __popcll(__ballot(t0)) + __popcll(__ballot(t1)) + __popcll(__ballot(t2));
        unsigned idxthr = 0xFFFFFFFFu;
        if (tcnt != need) {
            unsigned la = 0u, ha = 0xFFFFFFFFu;
            for (int it = 0; it < 32; ++it) {
                unsigned mid = la + ((ha - la) >> 1);
                int c = __popcll(__ballot(t0 && i0 <= mid)) + __popcll(__ballot(t1 && i1 <= mid))
                      + __popcll(__ballot(t2 && i2 <= mid));
                if (c >= need) ha = mid; else la = mid + 1;
            }
            idxthr = ha;
        }
        bool s0 = (d0 < th) || (t0 && i0 <= idxthr);
        bool s1 = (d1 < th) || (t1 && i1 <= idxthr);
        bool s2 = (d2 < th) || (t2 && i2 <= idxthr);

        unsigned long long m01 = k0 < k1 ? k0 : k1;
        unsigned long long mk  = m01 < k2 ? m01 : k2;
#pragma unroll
        for (int off = 32; off >= 1; off >>= 1) {
            unsigned long long o = __shfl_xor(mk, off, 64);
            mk = o < mk ? o : mk;
        }
        if (s0) { if (k0 == mk) neighL[wv][0] = (int)i0; else { int p = atomicAdd(&slot[wv], 1); neighL[wv][p] = (int)i0; } }
        if (s1) { if (k1 == mk) neighL[wv][0] = (int)i1; else { int p = atomicAdd(&slot[wv], 1); neighL[wv][p] = (int)i1; } }
        if (s2) { if (k2 == mk) neighL[wv][0] = (int)i2; else { int p = atomicAdd(&slot[wv], 1); neighL[wv][p] = (int)i2; } }
    }

    __syncthreads();   // Fb (aliased over cand+surv) written below; full drain OK here

    // ================= phase B: attention =================
    const ushort* fb = fbT + (size_t)b * NPTS * INC;
    ushort* Fw = FbB + wv * FWSZ;

    int nv = 0;
    if (l31 < KNBR) nv = neighL[wv][l31];
    float4 ncl = base[nv];

    float wm[8];
    {
        const float4* w8 = (const float4*)(wmlp8 + l31 * 8);
        float4 a = w8[0], bq = w8[1];
        wm[0] = a.x; wm[1] = a.y; wm[2] = a.z; wm[3] = a.w;
        wm[4] = bq.x; wm[5] = bq.y; wm[6] = bq.z; wm[7] = bq.w;
    }
    const float c0x = rlf(ncl.x, 0), c0y = rlf(ncl.y, 0), c0z = rlf(ncl.z, 0);

    // batched gather prefetch: all 20 feature loads issued before any use
    ushort fr[KNBR];
#pragma unroll
    for (int k = 0; k < KNBR; ++k) {
        int snk = __builtin_amdgcn_readlane(nv, k);
        fr[k] = fb[(size_t)snk * INC + l31];
    }

    // per-lane relative coords (lane k owns neighbor k); consumed via readlane
    float rxl = ncl.x - c0x, ryl = ncl.y - c0y, rzl = ncl.z - c0z;
    float disl = sqrtf(fmaf(rzl, rzl, fmaf(ryl, ryl, rxl * rxl)));

    float fmbase = wm[7];
    fmbase = fmaf(wm[0], c0x, fmbase); fmbase = fmaf(wm[1], c0y, fmbase);
    fmbase = fmaf(wm[2], c0z, fmbase);
#pragma unroll
    for (int k = 0; k < KNBR; ++k) {
        float fm = fmbase;
        fm = fmaf(wm[3], rlf(rxl, k), fm);
        fm = fmaf(wm[4], rlf(ryl, k), fm);
        fm = fmaf(wm[5], rlf(rzl, k), fm);
        fm = fmaf(wm[6], rlf(disl, k), fm);
        ushort fbits = hi ? f2bf(fm) : fr[k];
        Fw[k * 64 + (lane ^ ((k & 7) << 3))] = fbits;
    }

    const int rowA = (l31 < KNBR) ? l31 : (KNBR - 1);   // rows 20..31 = row-19 copies
    short8 Af[4];
#pragma unroll
    for (int kt = 0; kt < 4; ++kt) {
        int c0 = kt * 16 + 8 * hi;
        Af[kt] = *(const short8*)&Fw[rowA * 64 + (c0 ^ ((rowA & 7) << 3))];
    }

    // flipped orientation: lane k holds d-column -> lane-local softmax stats
    float mloc, zloc;
    {
        f32x16 af;
#pragma unroll
        for (int i = 0; i < 16; ++i) af[i] = 0.f;
        __builtin_amdgcn_s_setprio(1);
#pragma unroll
        for (int kt = 0; kt < 4; ++kt)
            af = __builtin_amdgcn_mfma_f32_32x32x16_bf16(wattF[kt * 64 + lane], Af[kt], af, 0, 0, 0);
        __builtin_amdgcn_s_setprio(0);
        float m0 = af[0];
#pragma unroll
        for (int i = 1; i < 16; ++i) m0 = fmaxf(m0, af[i]);
        float z0 = 0.f;
#pragma unroll
        for (int i = 0; i < 16; ++i) z0 += __expf(af[i] - m0);
        mloc = m0; zloc = z0;
    }
    {
        f32x16 af;
#pragma unroll
        for (int i = 0; i < 16; ++i) af[i] = 0.f;
        __builtin_amdgcn_s_setprio(1);
#pragma unroll
        for (int kt = 0; kt < 4; ++kt)
            af = __builtin_amdgcn_mfma_f32_32x32x16_bf16(wattF[(4 + kt) * 64 + lane], Af[kt], af, 0, 0, 0);
        __builtin_amdgcn_s_setprio(0);
        float m1 = af[0];
#pragma unroll
        for (int i = 1; i < 16; ++i) m1 = fmaxf(m1, af[i]);
        float z1 = 0.f;
#pragma unroll
        for (int i = 0; i < 16; ++i) z1 += __expf(af[i] - m1);
        float mn = fmaxf(mloc, m1);
        zloc = zloc * __expf(mloc - mn) + z1 * __expf(m1 - mn);
        mloc = mn;
    }
    float mo = fmaxf(mloc, __shfl_xor(mloc, 32, 64));
    float zs = zloc * __expf(mloc - mo);
    float Zk = zs + __shfl_xor(zs, 32, 64);
    float mzl = mo + __logf(Zk);      // log-fold: attn = exp(s - mzl)
    // stats for neighbor j live in lane j (and j+32): broadcast via readlane

    // original orientation + pooling, half at a time
    float pooled0 = 0.f, pooled1 = 0.f;
    {
        f32x16 acc;
#pragma unroll
        for (int i = 0; i < 16; ++i) acc[i] = 0.f;
        __builtin_amdgcn_s_setprio(1);
#pragma unroll
        for (int kt = 0; kt < 4; ++kt)
            acc = __builtin_amdgcn_mfma_f32_32x32x16_bf16(Af[kt], wattF[kt * 64 + lane], acc, 0, 0, 0);
        __builtin_amdgcn_s_setprio(0);
#pragma unroll
        for (int r = 0; r < 12; ++r) {
            int j = (r & 3) + 8 * (r >> 2) + 4 * hi;
            float a0 = __expf(acc[r] - rlf(mzl, j));
            float f0 = bf2f(Fw[j * 64 + (l31 ^ ((j & 7) << 3))]);
            float p0 = a0 * f0;
            if (r >= 8) p0 = hi ? 0.f : p0;           // j>=20 rows invalid
            pooled0 += p0;
        }
    }
    {
        f32x16 acc;
#pragma unroll
        for (int i = 0; i < 16; ++i) acc[i] = 0.f;
        __builtin_amdgcn_s_setprio(1);
#pragma unroll
        for (int kt = 0; kt < 4; ++kt)
            acc = __builtin_amdgcn_mfma_f32_32x32x16_bf16(Af[kt], wattF[(4 + kt) * 64 + lane], acc, 0, 0, 0);
        __builtin_amdgcn_s_setprio(0);
#pragma unroll
        for (int r = 0; r < 12; ++r) {
            int j = (r & 3) + 8 * (r >> 2) + 4 * hi;
            float a1 = __expf(acc[r] - rlf(mzl, j));
            float f1 = bf2f(Fw[j * 64 + ((32 + l31) ^ ((j & 7) << 3))]);
            float p1 = a1 * f1;
            if (r >= 8) p1 = hi ? 0.f : p1;
            pooled1 += p1;
        }
    }
    pooled0 += __shfl_xor(pooled0, 32, 64);
    pooled1 += __shfl_xor(pooled1, 32, 64);
    if (!hi) {
        pool[wv][l31]      = f2bf(pooled0);
        pool[wv][32 + l31] = f2bf(pooled1);
    }

    // epilogue: out = W_conv@pooled + W_out@feat (biases cancel in BN)
    f32x16 oa;
#pragma unroll
    for (int i = 0; i < 16; ++i) oa[i] = 0.f;
    __builtin_amdgcn_s_setprio(1);
#pragma unroll
    for (int kt = 0; kt < 4; ++kt) {
        short8 bb = *(const short8*)&pool[wv][kt * 16 + 8 * hi];
        oa = __builtin_amdgcn_mfma_f32_32x32x16_bf16(wconvF[kt * 64 + lane], bb, oa, 0, 0, 0);
    }
#pragma unroll
    for (int kt = 0; kt < 2; ++kt) {
        short8 bb = *(const short8*)(fb + (size_t)nb * INC + kt * 16 + 8 * hi);
        oa = __builtin_amdgcn_mfma_f32_32x32x16_bf16(woutF[kt * 64 + lane], bb, oa, 0, 0, 0);
    }
    __builtin_amdgcn_s_setprio(0);
#pragma unroll
    for (int r = 0; r < 16; ++r) {
        int o = (r & 3) + 8 * (r >> 2) + 4 * hi;
        if (l31 == 0) out[((size_t)(b * OUTC + o)) * NPTS + nb] = oa[r];
    }
}

// ---------------- kernel 2: fused BatchNorm (stats + normalize) ----------------
__global__ __launch_bounds__(256) void k_bn(float* __restrict__ of,
                                            const float* __restrict__ gamma,
                                            const float* __restrict__ beta) {
    const int c = blockIdx.x;
    const int tid = threadIdx.x;
    float s = 0.f, s2 = 0.f;
#pragma unroll
    for (int b = 0; b < BATCH; ++b) {
        const float4* p = (const float4*)(of + ((size_t)b * OUTC + c) * NPTS);
        for (int i = tid; i < NPTS / 4; i += 256) {
            float4 v = p[i];
            s += (v.x + v.y) + (v.z + v.w);
            s2 = fmaf(v.x, v.x, s2); s2 = fmaf(v.y, v.y, s2);
            s2 = fmaf(v.z, v.z, s2); s2 = fmaf(v.w, v.w, s2);
        }
    }
#pragma unroll
    for (int off = 32; off >= 1; off >>= 1) {
        s += __shfl_xor(s, off, 64);
        s2 += __shfl_xor(s2, off, 64);
    }
    __shared__ float rs[4], rs2[4];
    __shared__ float sc[2];
    if ((tid & 63) == 0) { rs[tid >> 6] = s; rs2[tid >> 6] = s2; }
    __syncthreads();
    if (tid == 0) {
        float S = (rs[0] + rs[1]) + (rs[2] + rs[3]);
        float S2 = (rs2[0] + rs2[1]) + (rs2[2] + rs2[3]);
        const float invn = 1.0f / (BATCH * NPTS);
        float mean = S * invn;
        float var = S2 * invn - mean * mean;
        float rstd = rsqrtf(var + EPSBN);
        float scale = rstd * gamma[c];
        sc[0] = scale;
        sc[1] = beta[c] - mean * scale;
    }
    __syncthreads();
    const float scale = sc[0], shift = sc[1];
#pragma unroll
    for (int b = 0; b < BATCH; ++b) {
        float4* p = (float4*)(of + ((size_t)b * OUTC + c) * NPTS);
        for (int i = tid; i < NPTS / 4; i += 256) {
            float4 v = p[i];
            v.x = fmaf(v.x, scale, shift);
            v.y = fmaf(v.y, scale, shift);
            v.z = fmaf(v.z, scale, shift);
            v.w = fmaf(v.w, scale, shift);
            p[i] = v;
        }
    }
}

// ---------------- launch ----------------
extern "C" void kernel_launch(void* const* d_in, const int* in_sizes, int n_in,
                              void* d_out, int out_size, void* d_ws, size_t ws_size,
                              hipStream_t stream) {
    const float* x      = (const float*)d_in[0];
    const float* feat   = (const float*)d_in[1];
    const float* w_mlp  = (const float*)d_in[2];
    const float* b_mlp  = (const float*)d_in[3];
    const float* w_att  = (const float*)d_in[4];
    const float* w_conv = (const float*)d_in[5];
    const float* w_out  = (const float*)d_in[7];
    const float* gamma  = (const float*)d_in[9];
    const float* beta   = (const float*)d_in[10];
    float* out = (float*)d_out;

    char* ws = (char*)d_ws;
    float4* xT4    = (float4*)ws;                          // 262144 B
    ushort* fbT    = (ushort*)(ws + 262144);               // 1048576 B
    short8* wattF  = (short8*)(ws + 1310976);              // 8192 B
    short8* wconvF = (short8*)(ws + 1319168);              // 4096 B
    short8* woutF  = (short8*)(ws + 1323264);              // 2048 B
    float*  wmlp8  = (float*)(ws + 1325312);               // 2048 B

    k_prep<<<(BATCH * INC * NPTS + 255) / 256 + 1, 256, 0, stream>>>(
        x, feat, xT4, fbT, w_att, w_conv, w_out, w_mlp, b_mlp,
        wattF, wconvF, woutF, wmlp8);
    k_fused<<<(BATCH * NPTS) / PPBK, 512, 0, stream>>>(xT4, fbT, wmlp8,
                                                       wattF, wconvF, woutF, out);
    k_bn<<<OUTC, 256, 0, stream>>>(out, gamma, beta);
}